// Round 1
// baseline (481.041 us; speedup 1.0000x reference)
//
#include <hip/hip_runtime.h>
#include <math.h>

#define NS 131072
#define DIM 256
#define CHUNK 512
#define WARM 128

// DPP-based butterfly add (stays on VALU pipe, no DS traffic)
template<int CTRL>
__device__ __forceinline__ float dpp_add(float x) {
    int y = __builtin_amdgcn_update_dpp(0, __float_as_int(x), CTRL, 0xf, 0xf, true);
    return x + __int_as_float(y);
}

// Pass 1: parallel-in-time HMM forward. 256 blocks; block c computes output
// steps [512c, 512c+512) after a 128-step warmup from a uniform guess
// (projective contraction of diag(ps)*T makes the warmup converge to the
// true trajectory below fp32 epsilon). Recursion is UNNORMALIZED:
//   v <- (256 * diag(ps_s) * T) @ v
// unnormalized v is written to out; pass 2 normalizes.
__global__ __launch_bounds__(512, 2) void hmm_pass1(
        const float* __restrict__ ps, const float* __restrict__ Tm,
        const float* __restrict__ state0, float* __restrict__ out) {
    __shared__ __align__(16) float sm[2][DIM];

    const int t   = threadIdx.x;
    const int c8  = t & 7;     // column-chunk: cols [32*c8, 32*c8+32)
    const int g   = t >> 3;    // bin group: bins [4g, 4g+4)
    const int blk = blockIdx.x;

    // Load this thread's 4x32 tile of T into registers, scaled by 256,
    // with per-lane XOR-permuted segment order so the per-step LDS reads
    // (addr = 128*c8 + 16*(r^c8)) hit all 32 banks exactly once.
    float4 Tr[8][4];
    #pragma unroll
    for (int r = 0; r < 8; ++r) {
        const int col = 32 * c8 + 4 * (r ^ c8);
        #pragma unroll
        for (int b = 0; b < 4; ++b) {
            float4 v = *reinterpret_cast<const float4*>(
                Tm + (size_t)(4 * g + b) * DIM + col);
            v.x *= 256.f; v.y *= 256.f; v.z *= 256.f; v.w *= 256.f;
            Tr[r][b] = v;
        }
    }

    // initial state: exact state0 for block 0 (no warmup needed there),
    // any positive vector for the rest (scale-invariant).
    if (t < DIM) sm[0][t] = (blk == 0) ? state0[t] : 1.0f;
    __syncthreads();

    const int sOut   = blk * CHUNK;
    const int sStart = (blk == 0) ? 0 : (sOut - WARM);
    const int sEnd   = sOut + CHUNK;

    // software-pipelined ps load (all 8 lanes of a group load the same
    // address -> L1 broadcast)
    float4 psc = *reinterpret_cast<const float4*>(
        ps + (size_t)sStart * DIM + 4 * g);
    int cur = 0;

    for (int s = sStart; s < sEnd; ++s) {
        const int sn = (s + 1 < NS) ? (s + 1) : (NS - 1);
        float4 psn = *reinterpret_cast<const float4*>(
            ps + (size_t)sn * DIM + 4 * g);

        float a0 = 0.f, a1 = 0.f, a2 = 0.f, a3 = 0.f;
        const float* sb = sm[cur];
        #pragma unroll
        for (int r = 0; r < 8; ++r) {
            float4 sv = *reinterpret_cast<const float4*>(
                sb + 32 * c8 + 4 * (r ^ c8));
            a0 += Tr[r][0].x * sv.x + Tr[r][0].y * sv.y
                + Tr[r][0].z * sv.z + Tr[r][0].w * sv.w;
            a1 += Tr[r][1].x * sv.x + Tr[r][1].y * sv.y
                + Tr[r][1].z * sv.z + Tr[r][1].w * sv.w;
            a2 += Tr[r][2].x * sv.x + Tr[r][2].y * sv.y
                + Tr[r][2].z * sv.z + Tr[r][2].w * sv.w;
            a3 += Tr[r][3].x * sv.x + Tr[r][3].y * sv.y
                + Tr[r][3].z * sv.z + Tr[r][3].w * sv.w;
        }

        // butterfly-sum over the 8 column-chunk lanes (xor 1, 2, 4):
        // quad_perm(1,0,3,2)=0xB1, quad_perm(2,3,0,1)=0x4E, half_mirror=0x141
        a0 = dpp_add<0xB1>(a0); a0 = dpp_add<0x4E>(a0); a0 = dpp_add<0x141>(a0);
        a1 = dpp_add<0xB1>(a1); a1 = dpp_add<0x4E>(a1); a1 = dpp_add<0x141>(a1);
        a2 = dpp_add<0xB1>(a2); a2 = dpp_add<0x4E>(a2); a2 = dpp_add<0x141>(a2);
        a3 = dpp_add<0xB1>(a3); a3 = dpp_add<0x4E>(a3); a3 = dpp_add<0x141>(a3);

        float4 pn;
        pn.x = a0 * psc.x; pn.y = a1 * psc.y;
        pn.z = a2 * psc.z; pn.w = a3 * psc.w;

        if (c8 == 0) {
            *reinterpret_cast<float4*>(&sm[cur ^ 1][4 * g]) = pn;
            if (s >= sOut) {
                *reinterpret_cast<float4*>(out + (size_t)s * DIM + 4 * g) = pn;
            }
        }

        // raw barrier: drain LDS only. Do NOT use __syncthreads() -- its
        // vmcnt(0) would serialize the ps prefetch + probs stores per step.
        asm volatile("s_waitcnt lgkmcnt(0)" ::: "memory");
        __builtin_amdgcn_s_barrier();
        asm volatile("" ::: "memory");

        psc = psn;
        cur ^= 1;
    }
}

// Pass 2: one wave per row. Normalize v in place, compute std.
__global__ __launch_bounds__(256) void hmm_pass2(float* __restrict__ out) {
    const int lane = threadIdx.x & 63;
    const int wid  = blockIdx.x * (blockDim.x >> 6) + (threadIdx.x >> 6);
    const int nw   = gridDim.x * (blockDim.x >> 6);
    float* stdv = out + (size_t)NS * DIM;

    for (int row = wid; row < NS; row += nw) {
        float4 v = *reinterpret_cast<float4*>(out + (size_t)row * DIM + 4 * lane);
        const float j0 = (float)(4 * lane);
        const float b0 = 30.f + 0.703125f * j0;
        const float b1 = 30.f + 0.703125f * (j0 + 1.f);
        const float b2 = 30.f + 0.703125f * (j0 + 2.f);
        const float b3 = 30.f + 0.703125f * (j0 + 3.f);

        float sS = v.x + v.y + v.z + v.w;
        float e1 = v.x * b0 + v.y * b1 + v.z * b2 + v.w * b3;
        float e2 = v.x * b0 * b0 + v.y * b1 * b1 + v.z * b2 * b2 + v.w * b3 * b3;

        #pragma unroll
        for (int k = 1; k < 64; k <<= 1) {
            sS += __shfl_xor(sS, k);
            e1 += __shfl_xor(e1, k);
            e2 += __shfl_xor(e2, k);
        }

        const float inv = 1.f / sS;
        v.x *= inv; v.y *= inv; v.z *= inv; v.w *= inv;
        *reinterpret_cast<float4*>(out + (size_t)row * DIM + 4 * lane) = v;

        if (lane == 0) {
            const float m   = e1 * inv;
            const float var = e2 * inv - m * m;
            stdv[row] = sqrtf(var > 0.f ? var : 0.f);
        }
    }
}

extern "C" void kernel_launch(void* const* d_in, const int* in_sizes, int n_in,
                              void* d_out, int out_size, void* d_ws, size_t ws_size,
                              hipStream_t stream) {
    const float* ps     = (const float*)d_in[0];
    const float* Tm     = (const float*)d_in[1];
    const float* state0 = (const float*)d_in[2];
    float* out = (float*)d_out;

    hmm_pass1<<<dim3(NS / CHUNK), dim3(512), 0, stream>>>(ps, Tm, state0, out);
    hmm_pass2<<<dim3(2048), dim3(256), 0, stream>>>(out);
}